// Round 5
// baseline (182.674 us; speedup 1.0000x reference)
//
#include <hip/hip_runtime.h>
#include <cstddef>

#define DIN 128
#define DOUT 64
#define BKT_SHIFT 7            // 128 dst nodes per bucket
#define BKT_NODES 128
#define CAP 2680               // per-bucket raw-edge capacity (mean 2048, +14 sigma)
#define CAPP 2816              // CSR capacity = CAP + 128 self-loops, rounded
#define MAXB 800               // >= NB = 782
#define EPB 4096               // edges per mscatter block
#define KITER (EPB / 256)

typedef __attribute__((ext_vector_type(8))) short bf16x8;
typedef __attribute__((ext_vector_type(4))) float f32x4;

__device__ __forceinline__ float leakyrelu(float v) { return v > 0.f ? v : 0.2f * v; }

__device__ __forceinline__ float bf2f(unsigned short v) {
    return __uint_as_float((unsigned)v << 16);
}
__device__ __forceinline__ unsigned short f2bf(float f) {
    unsigned u = __float_as_uint(f);
    unsigned r = ((u >> 16) & 1u) + 0x7FFFu;
    return (unsigned short)((u + r) >> 16);
}
__device__ __forceinline__ unsigned cvtpk(float lo, float hi) {
    unsigned r;
    asm volatile("v_cvt_pk_bf16_f32 %0, %1, %2" : "=v"(r) : "v"(lo), "v"(hi));
    return r;
}
__device__ __forceinline__ bf16x8 cvt8(f32x4 lo, f32x4 hi) {
    union { bf16x8 v; unsigned u[4]; } cv;
    cv.u[0] = cvtpk(lo[0], lo[1]);
    cv.u[1] = cvtpk(lo[2], lo[3]);
    cv.u[2] = cvtpk(hi[0], hi[1]);
    cv.u[3] = cvtpk(hi[2], hi[3]);
    return cv.v;
}

// ---------------- zero line-padded per-bucket cursors ----------------
__global__ __launch_bounds__(256) void k_zero(int* __restrict__ gcur, int n) {
    int i = blockIdx.x * 256 + threadIdx.x;
    if (i < n) gcur[i] = 0;
}

// ---------------- MFMA transform: hb = bf16(x@W), asrc/adst scores ----------------
// Per wave: 16 nodes x 64 cols via 16x16x32 bf16 MFMA.
// A frag: row = lane&15, k = kb*32 + (lane>>4)*8 + i.  B frag: col = lane&15, same k.
// C/D: col = lane&15, row = (lane>>4)*4 + reg  [m89-verified layout].
__global__ __launch_bounds__(256) void k_transform(
    const float* __restrict__ x, const float* __restrict__ W,
    const float* __restrict__ att_src, const float* __restrict__ att_dst,
    unsigned short* __restrict__ hb, float* __restrict__ asrc, float* __restrict__ adst, int N)
{
    const int tid = threadIdx.x;
    const int lane = tid & 63, g = lane >> 4, c15 = lane & 15;
    const int n0w = blockIdx.x * 64 + (tid >> 6) * 16;
    if (n0w >= N) return;

    // A fragments: this wave's 16 node rows of x, converted to bf16
    const int arow = min(n0w + c15, N - 1);
    const float* xr = x + (size_t)arow * DIN + g * 8;
    bf16x8 afrag[4];
    #pragma unroll
    for (int kb = 0; kb < 4; ++kb) {
        f32x4 lo = *reinterpret_cast<const f32x4*>(xr + kb * 32);
        f32x4 hi = *reinterpret_cast<const f32x4*>(xr + kb * 32 + 4);
        afrag[kb] = cvt8(lo, hi);
    }

    f32x4 acc[4];
    #pragma unroll
    for (int nt = 0; nt < 4; ++nt) {
        f32x4 a = {0.f, 0.f, 0.f, 0.f};
        #pragma unroll
        for (int kb = 0; kb < 4; ++kb) {
            const float* wp = W + (size_t)(kb * 32 + g * 8) * DOUT + nt * 16 + c15;
            f32x4 lo, hi;
            #pragma unroll
            for (int i = 0; i < 4; ++i) lo[i] = wp[i * DOUT];
            #pragma unroll
            for (int i = 0; i < 4; ++i) hi[i] = wp[(i + 4) * DOUT];
            a = __builtin_amdgcn_mfma_f32_16x16x32_bf16(afrag[kb], cvt8(lo, hi), a, 0, 0, 0);
        }
        acc[nt] = a;
    }

    // store h (bf16)
    #pragma unroll
    for (int nt = 0; nt < 4; ++nt)
        #pragma unroll
        for (int r = 0; r < 4; ++r) {
            int row = n0w + g * 4 + r;
            if (row < N) hb[(size_t)row * DOUT + nt * 16 + c15] = f2bf(acc[nt][r]);
        }

    // per-row dots with att vectors: partial per lane, reduce across 16-lane group
    float ps[4] = {0.f, 0.f, 0.f, 0.f}, pd[4] = {0.f, 0.f, 0.f, 0.f};
    #pragma unroll
    for (int nt = 0; nt < 4; ++nt) {
        float as = att_src[nt * 16 + c15];
        float ad = att_dst[nt * 16 + c15];
        #pragma unroll
        for (int r = 0; r < 4; ++r) {
            ps[r] = fmaf(acc[nt][r], as, ps[r]);
            pd[r] = fmaf(acc[nt][r], ad, pd[r]);
        }
    }
    #pragma unroll
    for (int off = 1; off < 16; off <<= 1)
        #pragma unroll
        for (int r = 0; r < 4; ++r) {
            ps[r] += __shfl_xor(ps[r], off);
            pd[r] += __shfl_xor(pd[r], off);
        }
    #pragma unroll
    for (int r = 0; r < 4; ++r) {
        int row = n0w + g * 4 + r;
        if (c15 == r && row < N) { asrc[row] = ps[r]; adst[row] = pd[r]; }
    }
}

// ---------------- multisplit scatter into per-bucket regions ----------------
__global__ __launch_bounds__(256) void k_mscatter(
    const int* __restrict__ src, const int* __restrict__ dst,
    int* __restrict__ gcurP, unsigned int* __restrict__ sbuf, int E, int NB)
{
    __shared__ int hist[MAXB];
    __shared__ int base[MAXB];
    const int tid = threadIdx.x;
    const int e0 = blockIdx.x * EPB;

    for (int i = tid; i < NB; i += 256) hist[i] = 0;
    __syncthreads();

    int dcache[KITER];
    #pragma unroll
    for (int k = 0; k < KITER; ++k) {
        int e = e0 + k * 256 + tid;
        dcache[k] = (e < E) ? dst[e] : -1;
        if (dcache[k] >= 0) atomicAdd(&hist[dcache[k] >> BKT_SHIFT], 1);
    }
    __syncthreads();

    for (int i = tid; i < NB; i += 256) {
        int c = hist[i];
        base[i] = c ? atomicAdd(&gcurP[i * 16], c) : 0;   // line-padded cursors
        hist[i] = 0;   // reuse as running rank
    }
    __syncthreads();

    #pragma unroll
    for (int k = 0; k < KITER; ++k) {
        int d = dcache[k];
        if (d >= 0) {
            int e = e0 + k * 256 + tid;
            int b = d >> BKT_SHIFT;
            int r = atomicAdd(&hist[b], 1);
            int idx = base[b] + r;
            if (idx < CAP)
                sbuf[(size_t)b * CAP + idx] =
                    (unsigned)src[e] | ((unsigned)(d & (BKT_NODES - 1)) << 17);
        }
    }
}

// ---------------- per-bucket CSR build + alpha + einv (writes global CSR) ----------------
__global__ __launch_bounds__(512) void k_csr(
    const int* __restrict__ gcurP, const unsigned int* __restrict__ sbuf,
    const float* __restrict__ asrc, const float* __restrict__ adst,
    unsigned int* __restrict__ csort, float* __restrict__ calpha,
    int* __restrict__ nstart, int* __restrict__ nend, float* __restrict__ einv, int N)
{
    __shared__ unsigned int el[CAP];
    __shared__ int hist[BKT_NODES], hist2[BKT_NODES], offs[BKT_NODES + 1];
    __shared__ float ssumL[BKT_NODES], selfE[BKT_NODES];

    const int tid = threadIdx.x;
    const int b = blockIdx.x;
    const int n0 = b << BKT_SHIFT;
    const int nn = min(BKT_NODES, N - n0);
    int cnt = gcurP[b * 16]; if (cnt > CAP) cnt = CAP;

    for (int i = tid; i < cnt; i += 512) el[i] = sbuf[(size_t)b * CAP + i];
    if (tid < BKT_NODES) { hist[tid] = 0; hist2[tid] = 0; }
    if (tid < nn) {
        int n = n0 + tid;
        float se = __expf(leakyrelu(asrc[n] + adst[n]));
        selfE[tid] = se;
        ssumL[tid] = se;
    }
    __syncthreads();

    for (int i = tid; i < cnt; i += 512) atomicAdd(&hist[el[i] >> 17], 1);
    __syncthreads();

    // inclusive scan of (hist[ln]+1) -> offs[1..128]; +1 reserves the self-loop slot
    if (tid < BKT_NODES) offs[tid + 1] = hist[tid] + 1;
    if (tid == 0) offs[0] = 0;
    __syncthreads();
    for (int off = 1; off < BKT_NODES; off <<= 1) {
        int v = 0;
        if (tid < BKT_NODES && tid >= off) v = offs[tid + 1 - off];
        __syncthreads();
        if (tid < BKT_NODES && tid >= off) offs[tid + 1] += v;
        __syncthreads();
    }

    const size_t gbase = (size_t)b * CAPP;
    for (int i = tid; i < cnt; i += 512) {
        unsigned int e = el[i];
        int ln = e >> 17;
        unsigned int s = e & 0x1FFFF;
        int r = atomicAdd(&hist2[ln], 1);
        int p = offs[ln] + r;
        float a = __expf(leakyrelu(asrc[s] + adst[n0 + ln]));
        csort[gbase + p] = s;
        calpha[gbase + p] = a;
        atomicAdd(&ssumL[ln], a);
    }
    __syncthreads();

    if (tid < nn) {
        int n = n0 + tid;
        int pend = offs[tid + 1];
        csort[gbase + pend - 1] = (unsigned)n;        // self-loop as a real edge
        calpha[gbase + pend - 1] = selfE[tid];
        nstart[n] = (int)gbase + offs[tid];
        nend[n]   = (int)gbase + pend;
        einv[n]   = 1.f / (ssumL[tid] + 1e-16f);
    }
}

// ---------------- aggregation: one wave per node, full occupancy ----------------
__global__ __launch_bounds__(256) void k_agg(
    const int* __restrict__ nstart, const int* __restrict__ nend,
    const unsigned int* __restrict__ csort, const float* __restrict__ calpha,
    const unsigned short* __restrict__ hb, const float* __restrict__ einv,
    const float* __restrict__ bias, float* __restrict__ out, int N)
{
    const int lane = threadIdx.x & 63;
    const int n = blockIdx.x * 4 + (threadIdx.x >> 6);
    if (n >= N) return;
    const int st = nstart[n], en = nend[n];
    float acc0 = 0.f, acc1 = 0.f;
    int j = st;
    for (; j + 1 < en; j += 2) {
        unsigned s0 = csort[j], s1 = csort[j + 1];
        float a0 = calpha[j], a1 = calpha[j + 1];
        acc0 = fmaf(a0, bf2f(hb[(size_t)s0 * DOUT + lane]), acc0);
        acc1 = fmaf(a1, bf2f(hb[(size_t)s1 * DOUT + lane]), acc1);
    }
    if (j < en) acc0 = fmaf(calpha[j], bf2f(hb[(size_t)csort[j] * DOUT + lane]), acc0);
    out[(size_t)n * DOUT + lane] = (acc0 + acc1) * einv[n] + bias[lane];
}

extern "C" void kernel_launch(void* const* d_in, const int* in_sizes, int n_in,
                              void* d_out, int out_size, void* d_ws, size_t ws_size,
                              hipStream_t stream)
{
    const float* x       = (const float*)d_in[0];
    const int*   edge    = (const int*)d_in[1];   // [2, E]: row 0 = src, row 1 = dst
    const float* W       = (const float*)d_in[2];
    const float* att_src = (const float*)d_in[3];
    const float* att_dst = (const float*)d_in[4];
    const float* bias    = (const float*)d_in[5];

    const int N = in_sizes[0] / DIN;
    const int E = in_sizes[1] / 2;
    const int* src = edge;
    const int* dst = edge + E;
    float* out = (float*)d_out;

    const int NB = (N + BKT_NODES - 1) >> BKT_SHIFT;   // 782

    // ws layout: hb(u16 N*64) | asrc | adst | einv | nstart | nend | gcurP(NB*16) | sbuf(NB*CAP) | csort(NB*CAPP) | calpha(NB*CAPP)
    unsigned short* hb = (unsigned short*)d_ws;
    float* asrc = (float*)(hb + (size_t)N * DOUT);
    float* adst = asrc + N;
    float* einv = adst + N;
    int* nstart = (int*)(einv + N);
    int* nend   = nstart + N;
    int* gcurP  = nend + N;
    unsigned int* sbuf   = (unsigned int*)(gcurP + (size_t)NB * 16);
    unsigned int* csort  = sbuf + (size_t)NB * CAP;
    float* calpha        = (float*)(csort + (size_t)NB * CAPP);

    k_zero     <<<(NB * 16 + 255) / 256, 256, 0, stream>>>(gcurP, NB * 16);
    k_transform<<<(N + 63) / 64, 256, 0, stream>>>(x, W, att_src, att_dst, hb, asrc, adst, N);
    k_mscatter <<<(E + EPB - 1) / EPB, 256, 0, stream>>>(src, dst, gcurP, sbuf, E, NB);
    k_csr      <<<NB, 512, 0, stream>>>(gcurP, sbuf, asrc, adst, csort, calpha, nstart, nend, einv, N);
    k_agg      <<<(N + 3) / 4, 256, 0, stream>>>(nstart, nend, csort, calpha, hb, einv, bias, out, N);
}

// Round 6
// 152.426 us; speedup vs baseline: 1.1984x; 1.1984x over previous
//
#include <hip/hip_runtime.h>
#include <cstddef>

#define DIN 128
#define DOUT 64
#define BKT_SHIFT 7            // 128 dst nodes per bucket
#define BKT_NODES 128
#define CAP 2680               // per-bucket raw-edge capacity (mean 2048, +14 sigma)
#define CAPP 2816              // CSR capacity = CAP + 128 self-loops, rounded
#define MAXB 800               // >= NB = 782
#define EPB 2048               // edges per mscatter block
#define KITER (EPB / 256)

typedef __attribute__((ext_vector_type(8))) short bf16x8;
typedef __attribute__((ext_vector_type(4))) float f32x4;

__device__ __forceinline__ float leakyrelu(float v) { return v > 0.f ? v : 0.2f * v; }

__device__ __forceinline__ float bf2f(unsigned short v) {
    return __uint_as_float((unsigned)v << 16);
}
__device__ __forceinline__ unsigned short f2bf(float f) {
    unsigned u = __float_as_uint(f);
    unsigned r = ((u >> 16) & 1u) + 0x7FFFu;
    return (unsigned short)((u + r) >> 16);
}
__device__ __forceinline__ unsigned cvtpk(float lo, float hi) {
    unsigned r;
    asm volatile("v_cvt_pk_bf16_f32 %0, %1, %2" : "=v"(r) : "v"(lo), "v"(hi));
    return r;
}
__device__ __forceinline__ bf16x8 cvt8(f32x4 lo, f32x4 hi) {
    union { bf16x8 v; unsigned u[4]; } cv;
    cv.u[0] = cvtpk(lo[0], lo[1]);
    cv.u[1] = cvtpk(lo[2], lo[3]);
    cv.u[2] = cvtpk(hi[0], hi[1]);
    cv.u[3] = cvtpk(hi[2], hi[3]);
    return cv.v;
}

// ---------------- MFMA transform (+ folds gcurP zeroing) ----------------
// Per wave: 16 nodes x 64 cols via 16x16x32 bf16 MFMA.  [m89-verified C/D layout]
__global__ __launch_bounds__(256) void k_transform(
    const float* __restrict__ x, const float* __restrict__ W,
    const float* __restrict__ att_src, const float* __restrict__ att_dst,
    unsigned short* __restrict__ hb, float* __restrict__ asrc, float* __restrict__ adst,
    int* __restrict__ gcurP, int NBZ, int N)
{
    const int tid = threadIdx.x;
    // folded: zero the line-padded bucket cursors (first 49 blocks cover NBZ=12512)
    const int zi = blockIdx.x * 256 + tid;
    if (zi < NBZ) gcurP[zi] = 0;

    const int lane = tid & 63, g = lane >> 4, c15 = lane & 15;
    const int n0w = blockIdx.x * 64 + (tid >> 6) * 16;
    if (n0w >= N) return;

    const int arow = min(n0w + c15, N - 1);
    const float* xr = x + (size_t)arow * DIN + g * 8;
    bf16x8 afrag[4];
    #pragma unroll
    for (int kb = 0; kb < 4; ++kb) {
        f32x4 lo = *reinterpret_cast<const f32x4*>(xr + kb * 32);
        f32x4 hi = *reinterpret_cast<const f32x4*>(xr + kb * 32 + 4);
        afrag[kb] = cvt8(lo, hi);
    }

    f32x4 acc[4];
    #pragma unroll
    for (int nt = 0; nt < 4; ++nt) {
        f32x4 a = {0.f, 0.f, 0.f, 0.f};
        #pragma unroll
        for (int kb = 0; kb < 4; ++kb) {
            const float* wp = W + (size_t)(kb * 32 + g * 8) * DOUT + nt * 16 + c15;
            f32x4 lo, hi;
            #pragma unroll
            for (int i = 0; i < 4; ++i) lo[i] = wp[i * DOUT];
            #pragma unroll
            for (int i = 0; i < 4; ++i) hi[i] = wp[(i + 4) * DOUT];
            a = __builtin_amdgcn_mfma_f32_16x16x32_bf16(afrag[kb], cvt8(lo, hi), a, 0, 0, 0);
        }
        acc[nt] = a;
    }

    #pragma unroll
    for (int nt = 0; nt < 4; ++nt)
        #pragma unroll
        for (int r = 0; r < 4; ++r) {
            int row = n0w + g * 4 + r;
            if (row < N) hb[(size_t)row * DOUT + nt * 16 + c15] = f2bf(acc[nt][r]);
        }

    float ps[4] = {0.f, 0.f, 0.f, 0.f}, pd[4] = {0.f, 0.f, 0.f, 0.f};
    #pragma unroll
    for (int nt = 0; nt < 4; ++nt) {
        float as = att_src[nt * 16 + c15];
        float ad = att_dst[nt * 16 + c15];
        #pragma unroll
        for (int r = 0; r < 4; ++r) {
            ps[r] = fmaf(acc[nt][r], as, ps[r]);
            pd[r] = fmaf(acc[nt][r], ad, pd[r]);
        }
    }
    #pragma unroll
    for (int off = 1; off < 16; off <<= 1)
        #pragma unroll
        for (int r = 0; r < 4; ++r) {
            ps[r] += __shfl_xor(ps[r], off);
            pd[r] += __shfl_xor(pd[r], off);
        }
    #pragma unroll
    for (int r = 0; r < 4; ++r) {
        int row = n0w + g * 4 + r;
        if (c15 == r && row < N) { asrc[row] = ps[r]; adst[row] = pd[r]; }
    }
}

// ---------------- multisplit scatter into per-bucket regions ----------------
__global__ __launch_bounds__(256) void k_mscatter(
    const int* __restrict__ src, const int* __restrict__ dst,
    int* __restrict__ gcurP, unsigned int* __restrict__ sbuf, int E, int NB)
{
    __shared__ int hist[MAXB];
    __shared__ int base[MAXB];
    const int tid = threadIdx.x;
    const int e0 = blockIdx.x * EPB;

    for (int i = tid; i < NB; i += 256) hist[i] = 0;
    __syncthreads();

    int dcache[KITER];
    #pragma unroll
    for (int k = 0; k < KITER; ++k) {
        int e = e0 + k * 256 + tid;
        dcache[k] = (e < E) ? dst[e] : -1;
        if (dcache[k] >= 0) atomicAdd(&hist[dcache[k] >> BKT_SHIFT], 1);
    }
    __syncthreads();

    for (int i = tid; i < NB; i += 256) {
        int c = hist[i];
        base[i] = c ? atomicAdd(&gcurP[i * 16], c) : 0;   // line-padded cursors
        hist[i] = 0;   // reuse as running rank
    }
    __syncthreads();

    #pragma unroll
    for (int k = 0; k < KITER; ++k) {
        int d = dcache[k];
        if (d >= 0) {
            int e = e0 + k * 256 + tid;
            int b = d >> BKT_SHIFT;
            int r = atomicAdd(&hist[b], 1);
            int idx = base[b] + r;
            if (idx < CAP)
                sbuf[(size_t)b * CAP + idx] =
                    (unsigned)src[e] | ((unsigned)(d & (BKT_NODES - 1)) << 17);
        }
    }
}

// ---------------- per-bucket CSR build + alpha + einv ----------------
__global__ __launch_bounds__(512) void k_csr(
    const int* __restrict__ gcurP, const unsigned int* __restrict__ sbuf,
    const float* __restrict__ asrc, const float* __restrict__ adst,
    unsigned int* __restrict__ csort, float* __restrict__ calpha,
    int2* __restrict__ nspan, float* __restrict__ einv, int N)
{
    __shared__ unsigned int el[CAP];
    __shared__ int hist[BKT_NODES], hist2[BKT_NODES], offs[BKT_NODES + 1];
    __shared__ float ssumL[BKT_NODES], selfE[BKT_NODES];

    const int tid = threadIdx.x;
    const int b = blockIdx.x;
    const int n0 = b << BKT_SHIFT;
    const int nn = min(BKT_NODES, N - n0);
    int cnt = gcurP[b * 16]; if (cnt > CAP) cnt = CAP;

    for (int i = tid; i < cnt; i += 512) el[i] = sbuf[(size_t)b * CAP + i];
    if (tid < BKT_NODES) { hist[tid] = 0; hist2[tid] = 0; }
    if (tid < nn) {
        int n = n0 + tid;
        float se = __expf(leakyrelu(asrc[n] + adst[n]));
        selfE[tid] = se;
        ssumL[tid] = se;
    }
    __syncthreads();

    for (int i = tid; i < cnt; i += 512) atomicAdd(&hist[el[i] >> 17], 1);
    __syncthreads();

    // inclusive scan of (hist[ln]+1) -> offs[1..128]; +1 reserves the self-loop slot
    if (tid < BKT_NODES) offs[tid + 1] = hist[tid] + 1;
    if (tid == 0) offs[0] = 0;
    __syncthreads();
    for (int off = 1; off < BKT_NODES; off <<= 1) {
        int v = 0;
        if (tid < BKT_NODES && tid >= off) v = offs[tid + 1 - off];
        __syncthreads();
        if (tid < BKT_NODES && tid >= off) offs[tid + 1] += v;
        __syncthreads();
    }

    const size_t gbase = (size_t)b * CAPP;
    for (int i = tid; i < cnt; i += 512) {
        unsigned int e = el[i];
        int ln = e >> 17;
        unsigned int s = e & 0x1FFFF;
        int r = atomicAdd(&hist2[ln], 1);
        int p = offs[ln] + r;
        float a = __expf(leakyrelu(asrc[s] + adst[n0 + ln]));
        csort[gbase + p] = s;
        calpha[gbase + p] = a;
        atomicAdd(&ssumL[ln], a);
    }
    __syncthreads();

    if (tid < nn) {
        int n = n0 + tid;
        int pend = offs[tid + 1];
        csort[gbase + pend - 1] = (unsigned)n;        // self-loop as a real edge
        calpha[gbase + pend - 1] = selfE[tid];
        nspan[n] = make_int2((int)gbase + offs[tid], (int)gbase + pend);
        einv[n]  = 1.f / (ssumL[tid] + 1e-16f);
    }
}

// ---------------- aggregation: one wave per node, 8-deep gather pipeline ----------------
__global__ __launch_bounds__(256) void k_agg(
    const int2* __restrict__ nspan, const unsigned int* __restrict__ csort,
    const float* __restrict__ calpha, const unsigned short* __restrict__ hb,
    const float* __restrict__ einv, const float* __restrict__ bias,
    float* __restrict__ out, int N)
{
    const int lane = threadIdx.x & 63;
    const int n = blockIdx.x * 4 + (threadIdx.x >> 6);
    if (n >= N) return;
    const int2 span = nspan[n];
    // force segment bounds into SGPRs -> metadata loads become s_load (scalar pipe)
    const int st = __builtin_amdgcn_readfirstlane(span.x);
    const int en = __builtin_amdgcn_readfirstlane(span.y);

    float acc0 = 0.f, acc1 = 0.f, acc2 = 0.f, acc3 = 0.f;
    int j = st;
    for (; j + 8 <= en; j += 8) {
        unsigned sx[8]; float al[8], hv[8];
        #pragma unroll
        for (int q = 0; q < 8; ++q) { sx[q] = csort[j + q]; al[q] = calpha[j + q]; }
        #pragma unroll
        for (int q = 0; q < 8; ++q) hv[q] = bf2f(hb[(size_t)sx[q] * DOUT + lane]);
        acc0 = fmaf(al[0], hv[0], acc0);
        acc1 = fmaf(al[1], hv[1], acc1);
        acc2 = fmaf(al[2], hv[2], acc2);
        acc3 = fmaf(al[3], hv[3], acc3);
        acc0 = fmaf(al[4], hv[4], acc0);
        acc1 = fmaf(al[5], hv[5], acc1);
        acc2 = fmaf(al[6], hv[6], acc2);
        acc3 = fmaf(al[7], hv[7], acc3);
    }
    if (j + 4 <= en) {
        unsigned sx[4]; float al[4], hv[4];
        #pragma unroll
        for (int q = 0; q < 4; ++q) { sx[q] = csort[j + q]; al[q] = calpha[j + q]; }
        #pragma unroll
        for (int q = 0; q < 4; ++q) hv[q] = bf2f(hb[(size_t)sx[q] * DOUT + lane]);
        acc0 = fmaf(al[0], hv[0], acc0);
        acc1 = fmaf(al[1], hv[1], acc1);
        acc2 = fmaf(al[2], hv[2], acc2);
        acc3 = fmaf(al[3], hv[3], acc3);
        j += 4;
    }
    for (; j < en; ++j)
        acc0 = fmaf(calpha[j], bf2f(hb[(size_t)csort[j] * DOUT + lane]), acc0);

    out[(size_t)n * DOUT + lane] = (acc0 + acc1 + acc2 + acc3) * einv[n] + bias[lane];
}

extern "C" void kernel_launch(void* const* d_in, const int* in_sizes, int n_in,
                              void* d_out, int out_size, void* d_ws, size_t ws_size,
                              hipStream_t stream)
{
    const float* x       = (const float*)d_in[0];
    const int*   edge    = (const int*)d_in[1];   // [2, E]: row 0 = src, row 1 = dst
    const float* W       = (const float*)d_in[2];
    const float* att_src = (const float*)d_in[3];
    const float* att_dst = (const float*)d_in[4];
    const float* bias    = (const float*)d_in[5];

    const int N = in_sizes[0] / DIN;
    const int E = in_sizes[1] / 2;
    const int* src = edge;
    const int* dst = edge + E;
    float* out = (float*)d_out;

    const int NB = (N + BKT_NODES - 1) >> BKT_SHIFT;   // 782

    // ws layout: hb(u16 N*64) | asrc | adst | einv | nspan(int2 N) | gcurP(NB*16) | sbuf | csort | calpha
    unsigned short* hb = (unsigned short*)d_ws;
    float* asrc = (float*)(hb + (size_t)N * DOUT);
    float* adst = asrc + N;
    float* einv = adst + N;
    int2* nspan = (int2*)(einv + N);
    int* gcurP  = (int*)(nspan + N);
    unsigned int* sbuf   = (unsigned int*)(gcurP + (size_t)NB * 16);
    unsigned int* csort  = sbuf + (size_t)NB * CAP;
    float* calpha        = (float*)(csort + (size_t)NB * CAPP);

    k_transform<<<(N + 63) / 64, 256, 0, stream>>>(x, W, att_src, att_dst, hb, asrc, adst,
                                                   gcurP, NB * 16, N);
    k_mscatter <<<(E + EPB - 1) / EPB, 256, 0, stream>>>(src, dst, gcurP, sbuf, E, NB);
    k_csr      <<<NB, 512, 0, stream>>>(gcurP, sbuf, asrc, adst, csort, calpha, nspan, einv, N);
    k_agg      <<<(N + 3) / 4, 256, 0, stream>>>(nspan, csort, calpha, hb, einv, bias, out, N);
}

// Round 7
// 103.445 us; speedup vs baseline: 1.7659x; 1.4735x over previous
//
#include <hip/hip_runtime.h>
#include <cstddef>

#define DIN 128
#define DOUT 64
#define BKT_SHIFT 7            // 128 dst nodes per bucket
#define BKT_NODES 128
#define CAP 2680               // per-bucket edge capacity (mean 2046, +14 sigma)
#define CAPP 2816              // CSR capacity = CAP + 128 self-loops
#define MAXB 800               // >= NB = 782
#define EPB 8192               // edges per mscatter chunk
#define TW 784                 // table row width (NB+1 rounded)

typedef __attribute__((ext_vector_type(8))) short bf16x8;
typedef __attribute__((ext_vector_type(4))) float f32x4;

__device__ __forceinline__ float leakyrelu(float v) { return v > 0.f ? v : 0.2f * v; }

__device__ __forceinline__ float bf2f(unsigned short v) {
    return __uint_as_float((unsigned)v << 16);
}
__device__ __forceinline__ unsigned short f2bf(float f) {
    unsigned u = __float_as_uint(f);
    unsigned r = ((u >> 16) & 1u) + 0x7FFFu;
    return (unsigned short)((u + r) >> 16);
}
__device__ __forceinline__ unsigned cvtpk(float lo, float hi) {
    unsigned r;
    asm volatile("v_cvt_pk_bf16_f32 %0, %1, %2" : "=v"(r) : "v"(lo), "v"(hi));
    return r;
}
__device__ __forceinline__ bf16x8 cvt8(f32x4 lo, f32x4 hi) {
    union { bf16x8 v; unsigned u[4]; } cv;
    cv.u[0] = cvtpk(lo[0], lo[1]);
    cv.u[1] = cvtpk(lo[2], lo[3]);
    cv.u[2] = cvtpk(hi[0], hi[1]);
    cv.u[3] = cvtpk(hi[2], hi[3]);
    return cv.v;
}

// ---------------- MFMA transform: hb = bf16(x@W), asrc/adst scores ----------------
// Per wave: 16 nodes x 64 cols via 16x16x32 bf16 MFMA.  [m89-verified C/D layout]
__global__ __launch_bounds__(256) void k_transform(
    const float* __restrict__ x, const float* __restrict__ W,
    const float* __restrict__ att_src, const float* __restrict__ att_dst,
    unsigned short* __restrict__ hb, float* __restrict__ asrc, float* __restrict__ adst, int N)
{
    const int tid = threadIdx.x;
    const int lane = tid & 63, g = lane >> 4, c15 = lane & 15;
    const int n0w = blockIdx.x * 64 + (tid >> 6) * 16;
    if (n0w >= N) return;

    const int arow = min(n0w + c15, N - 1);
    const float* xr = x + (size_t)arow * DIN + g * 8;
    bf16x8 afrag[4];
    #pragma unroll
    for (int kb = 0; kb < 4; ++kb) {
        f32x4 lo = *reinterpret_cast<const f32x4*>(xr + kb * 32);
        f32x4 hi = *reinterpret_cast<const f32x4*>(xr + kb * 32 + 4);
        afrag[kb] = cvt8(lo, hi);
    }

    f32x4 acc[4];
    #pragma unroll
    for (int nt = 0; nt < 4; ++nt) {
        f32x4 a = {0.f, 0.f, 0.f, 0.f};
        #pragma unroll
        for (int kb = 0; kb < 4; ++kb) {
            const float* wp = W + (size_t)(kb * 32 + g * 8) * DOUT + nt * 16 + c15;
            f32x4 lo, hi;
            #pragma unroll
            for (int i = 0; i < 4; ++i) lo[i] = wp[i * DOUT];
            #pragma unroll
            for (int i = 0; i < 4; ++i) hi[i] = wp[(i + 4) * DOUT];
            a = __builtin_amdgcn_mfma_f32_16x16x32_bf16(afrag[kb], cvt8(lo, hi), a, 0, 0, 0);
        }
        acc[nt] = a;
    }

    #pragma unroll
    for (int nt = 0; nt < 4; ++nt)
        #pragma unroll
        for (int r = 0; r < 4; ++r) {
            int row = n0w + g * 4 + r;
            if (row < N) hb[(size_t)row * DOUT + nt * 16 + c15] = f2bf(acc[nt][r]);
        }

    float ps[4] = {0.f, 0.f, 0.f, 0.f}, pd[4] = {0.f, 0.f, 0.f, 0.f};
    #pragma unroll
    for (int nt = 0; nt < 4; ++nt) {
        float as = att_src[nt * 16 + c15];
        float ad = att_dst[nt * 16 + c15];
        #pragma unroll
        for (int r = 0; r < 4; ++r) {
            ps[r] = fmaf(acc[nt][r], as, ps[r]);
            pd[r] = fmaf(acc[nt][r], ad, pd[r]);
        }
    }
    #pragma unroll
    for (int off = 1; off < 16; off <<= 1)
        #pragma unroll
        for (int r = 0; r < 4; ++r) {
            ps[r] += __shfl_xor(ps[r], off);
            pd[r] += __shfl_xor(pd[r], off);
        }
    #pragma unroll
    for (int r = 0; r < 4; ++r) {
        int row = n0w + g * 4 + r;
        if (c15 == r && row < N) { asrc[row] = ps[r]; adst[row] = pd[r]; }
    }
}

// ---------------- LDS-staged multisplit: chunk-private sorted output ----------------
// Block c sorts its 8192 edges by bucket in LDS, writes them contiguously to
// sorted[c*EPB ...] (full-line, single-writer) + per-chunk offset table.
__global__ __launch_bounds__(1024) void k_mscatter(
    const int* __restrict__ src, const int* __restrict__ dst,
    unsigned int* __restrict__ sorted, int* __restrict__ table, int E, int NB)
{
    __shared__ unsigned int sbufL[EPB];     // 32 KB
    __shared__ int hist[MAXB];
    __shared__ int off[MAXB + 1];
    const int tid = threadIdx.x;
    const int c = blockIdx.x;
    const int e0 = c * EPB;
    const int cnt = min(EPB, E - e0);

    for (int i = tid; i < NB; i += 1024) hist[i] = 0;
    __syncthreads();

    unsigned pv[8]; int bv[8], rv[8];
    #pragma unroll
    for (int k = 0; k < 8; ++k) {
        int e = e0 + k * 1024 + tid;
        if (e < E) {
            int d = dst[e];
            pv[k] = (unsigned)src[e] | ((unsigned)(d & (BKT_NODES - 1)) << 17);
            bv[k] = d >> BKT_SHIFT;
            rv[k] = atomicAdd(&hist[bv[k]], 1);
        } else bv[k] = -1;
    }
    __syncthreads();

    // exclusive scan hist[0..NB-1] -> off[1..NB]; off[NB] == cnt
    if (tid < NB) off[tid + 1] = hist[tid];
    if (tid == 0) off[0] = 0;
    __syncthreads();
    for (int st = 1; st < NB; st <<= 1) {
        int add = 0;
        if (tid < NB && tid >= st) add = off[tid + 1 - st];
        __syncthreads();
        if (tid < NB && tid >= st) off[tid + 1] += add;
        __syncthreads();
    }

    // table row (coalesced, block-private)
    for (int i = tid; i <= NB; i += 1024) table[(size_t)c * TW + i] = off[i];

    // place into LDS at final intra-chunk position
    #pragma unroll
    for (int k = 0; k < 8; ++k)
        if (bv[k] >= 0) sbufL[off[bv[k]] + rv[k]] = pv[k];
    __syncthreads();

    // stream out: perfectly coalesced, full lines, single-writer region
    for (int i = tid; i < cnt; i += 1024)
        sorted[(size_t)c * EPB + i] = sbufL[i];
}

// ---------------- per-bucket CSR build: gather runs, softmax, packed edge stream ----------------
__global__ __launch_bounds__(512) void k_csr(
    const unsigned int* __restrict__ sorted, const int* __restrict__ table,
    const float* __restrict__ asrc, const float* __restrict__ adst,
    uint2* __restrict__ cpack, int2* __restrict__ nspan, float* __restrict__ einv,
    int N, int NC)
{
    __shared__ unsigned int el[CAP];
    __shared__ int cpre[513];
    __shared__ int hist[BKT_NODES], hist2[BKT_NODES], offs[BKT_NODES + 1];
    __shared__ float ssumL[BKT_NODES], selfE[BKT_NODES];

    const int tid = threadIdx.x;
    const int b = blockIdx.x;
    const int n0 = b << BKT_SHIFT;
    const int nn = min(BKT_NODES, N - n0);

    // gather this bucket's runs from all chunks
    int s0 = 0, len = 0;
    if (tid < NC) {
        s0 = table[(size_t)tid * TW + b];
        len = table[(size_t)tid * TW + b + 1] - s0;
    }
    if (tid < NC) cpre[tid + 1] = len;
    if (tid == 0) cpre[0] = 0;
    __syncthreads();
    for (int st = 1; st < NC; st <<= 1) {
        int add = 0;
        if (tid < NC && tid >= st) add = cpre[tid + 1 - st];
        __syncthreads();
        if (tid < NC && tid >= st) cpre[tid + 1] += add;
        __syncthreads();
    }
    if (tid < NC && len > 0) {
        int d0 = cpre[tid];
        const unsigned int* p = sorted + (size_t)tid * EPB + s0;
        int lim = min(len, CAP - d0);
        for (int i = 0; i < lim; ++i) el[d0 + i] = p[i];
    }
    if (tid < BKT_NODES) { hist[tid] = 0; hist2[tid] = 0; }
    if (tid < nn) {
        int n = n0 + tid;
        float se = __expf(leakyrelu(asrc[n] + adst[n]));
        selfE[tid] = se;
        ssumL[tid] = se;
    }
    __syncthreads();
    int cnt = cpre[NC]; if (cnt > CAP) cnt = CAP;

    for (int i = tid; i < cnt; i += 512) atomicAdd(&hist[el[i] >> 17], 1);
    __syncthreads();

    // inclusive scan of (hist[ln]+1) -> offs[1..128]; +1 reserves the self-loop slot
    if (tid < BKT_NODES) offs[tid + 1] = hist[tid] + 1;
    if (tid == 0) offs[0] = 0;
    __syncthreads();
    for (int off = 1; off < BKT_NODES; off <<= 1) {
        int v = 0;
        if (tid < BKT_NODES && tid >= off) v = offs[tid + 1 - off];
        __syncthreads();
        if (tid < BKT_NODES && tid >= off) offs[tid + 1] += v;
        __syncthreads();
    }

    const size_t gbase = (size_t)b * CAPP;
    for (int i = tid; i < cnt; i += 512) {
        unsigned int e = el[i];
        int ln = e >> 17;
        unsigned int s = e & 0x1FFFF;
        int r = atomicAdd(&hist2[ln], 1);
        int p = offs[ln] + r;
        float a = __expf(leakyrelu(asrc[s] + adst[n0 + ln]));
        cpack[gbase + p] = make_uint2(s, __float_as_uint(a));
        atomicAdd(&ssumL[ln], a);
    }
    __syncthreads();

    if (tid < nn) {
        int n = n0 + tid;
        int pend = offs[tid + 1];
        cpack[gbase + pend - 1] = make_uint2((unsigned)n, __float_as_uint(selfE[tid]));
        nspan[n] = make_int2((int)gbase + offs[tid], (int)gbase + pend);
        einv[n]  = 1.f / (ssumL[tid] + 1e-16f);
    }
}

// ---------------- aggregation: one wave per node, 8-deep gather pipeline ----------------
__global__ __launch_bounds__(256) void k_agg(
    const int2* __restrict__ nspan, const uint2* __restrict__ cpack,
    const unsigned short* __restrict__ hb, const float* __restrict__ einv,
    const float* __restrict__ bias, float* __restrict__ out, int N)
{
    const int lane = threadIdx.x & 63;
    const int n = blockIdx.x * 4 + (threadIdx.x >> 6);
    if (n >= N) return;
    const int2 span = nspan[n];
    const int st = __builtin_amdgcn_readfirstlane(span.x);
    const int en = __builtin_amdgcn_readfirstlane(span.y);

    float acc0 = 0.f, acc1 = 0.f, acc2 = 0.f, acc3 = 0.f;
    int j = st;
    for (; j + 8 <= en; j += 8) {
        uint2 md[8]; float hv[8];
        #pragma unroll
        for (int q = 0; q < 8; ++q) md[q] = cpack[j + q];
        #pragma unroll
        for (int q = 0; q < 8; ++q) hv[q] = bf2f(hb[(size_t)md[q].x * DOUT + lane]);
        acc0 = fmaf(__uint_as_float(md[0].y), hv[0], acc0);
        acc1 = fmaf(__uint_as_float(md[1].y), hv[1], acc1);
        acc2 = fmaf(__uint_as_float(md[2].y), hv[2], acc2);
        acc3 = fmaf(__uint_as_float(md[3].y), hv[3], acc3);
        acc0 = fmaf(__uint_as_float(md[4].y), hv[4], acc0);
        acc1 = fmaf(__uint_as_float(md[5].y), hv[5], acc1);
        acc2 = fmaf(__uint_as_float(md[6].y), hv[6], acc2);
        acc3 = fmaf(__uint_as_float(md[7].y), hv[7], acc3);
    }
    if (j + 4 <= en) {
        uint2 md[4]; float hv[4];
        #pragma unroll
        for (int q = 0; q < 4; ++q) md[q] = cpack[j + q];
        #pragma unroll
        for (int q = 0; q < 4; ++q) hv[q] = bf2f(hb[(size_t)md[q].x * DOUT + lane]);
        acc0 = fmaf(__uint_as_float(md[0].y), hv[0], acc0);
        acc1 = fmaf(__uint_as_float(md[1].y), hv[1], acc1);
        acc2 = fmaf(__uint_as_float(md[2].y), hv[2], acc2);
        acc3 = fmaf(__uint_as_float(md[3].y), hv[3], acc3);
        j += 4;
    }
    for (; j < en; ++j) {
        uint2 md = cpack[j];
        acc0 = fmaf(__uint_as_float(md.y), bf2f(hb[(size_t)md.x * DOUT + lane]), acc0);
    }

    out[(size_t)n * DOUT + lane] = (acc0 + acc1 + acc2 + acc3) * einv[n] + bias[lane];
}

extern "C" void kernel_launch(void* const* d_in, const int* in_sizes, int n_in,
                              void* d_out, int out_size, void* d_ws, size_t ws_size,
                              hipStream_t stream)
{
    const float* x       = (const float*)d_in[0];
    const int*   edge    = (const int*)d_in[1];   // [2, E]: row 0 = src, row 1 = dst
    const float* W       = (const float*)d_in[2];
    const float* att_src = (const float*)d_in[3];
    const float* att_dst = (const float*)d_in[4];
    const float* bias    = (const float*)d_in[5];

    const int N = in_sizes[0] / DIN;
    const int E = in_sizes[1] / 2;
    const int* src = edge;
    const int* dst = edge + E;
    float* out = (float*)d_out;

    const int NB = (N + BKT_NODES - 1) >> BKT_SHIFT;   // 782
    const int NC = (E + EPB - 1) / EPB;                // 196

    // ws layout (4B units): hb(N*32 u32) | asrc N | adst N | einv N | nspan 2N |
    //                       sorted NC*EPB | table NC*TW | cpack NB*CAPP*2
    unsigned short* hb = (unsigned short*)d_ws;
    float* asrc = (float*)(hb + (size_t)N * DOUT);
    float* adst = asrc + N;
    float* einv = adst + N;
    int2* nspan = (int2*)(einv + N);
    unsigned int* sorted = (unsigned int*)(nspan + N);
    int* table = (int*)(sorted + (size_t)NC * EPB);
    uint2* cpack = (uint2*)(table + (size_t)NC * TW);

    k_transform<<<(N + 63) / 64, 256, 0, stream>>>(x, W, att_src, att_dst, hb, asrc, adst, N);
    k_mscatter <<<NC, 1024, 0, stream>>>(src, dst, sorted, table, E, NB);
    k_csr      <<<NB, 512, 0, stream>>>(sorted, table, asrc, adst, cpack, nspan, einv, N, NC);
    k_agg      <<<(N + 3) / 4, 256, 0, stream>>>(nspan, cpack, hb, einv, bias, out, N);
}